// Round 1
// baseline (478.387 us; speedup 1.0000x reference)
//
#include <hip/hip_runtime.h>
#include <math.h>

#define ROI 7
#define NC 256          // channels per modality
#define HH 128
#define WW 128
#define HW (HH * WW)    // 16384

// ---------------------------------------------------------------------------
// Owner map: owner[b][y][x] = max anchor index n whose scattered 7x7 patch
// covers (y,x), else -1. Sequential overwrite == "last (max) anchor wins".
// atomicMax is associative -> deterministic.
// ---------------------------------------------------------------------------
__global__ void init_owner_k(int* __restrict__ owner, int n) {
    int i = blockIdx.x * blockDim.x + threadIdx.x;
    if (i < n) owner[i] = -1;
}

__global__ void mark_owner_k(const float* __restrict__ anchors,
                             int* __restrict__ owner, int B, int N) {
    int i = blockIdx.x * blockDim.x + threadIdx.x;
    int total = B * N * 49;
    if (i >= total) return;
    int p = i % 49;
    int bn = i / 49;
    int n = bn % N;
    int b = bn / N;
    float ax = anchors[(size_t)(b * N + n) * 3 + 0];
    float ay = anchors[(size_t)(b * N + n) * 3 + 1];
    int x0 = (int)truncf(ax - 3.5f); x0 = min(max(x0, 0), WW - ROI);
    int y0 = (int)truncf(ay - 3.5f); y0 = min(max(y0, 0), HH - ROI);
    int x = x0 + (p % 7);
    int y = y0 + (p / 7);
    atomicMax(&owner[((size_t)b << 14) + (y << 7) + x], n);
}

// ---------------------------------------------------------------------------
// Global fusion: per-pixel 2-logit 1x1 conv over 512 channels -> softmax ->
// per-channel blend. Thread = pixel (lanes over w => coalesced per channel).
// Pixels owned by an ROI are skipped entirely (fully overwritten later).
// ---------------------------------------------------------------------------
__global__ __launch_bounds__(256) void fuse_global_k(
        const float* __restrict__ rgb, const float* __restrict__ tir,
        const float* __restrict__ wg, const float* __restrict__ bg,
        const int* __restrict__ owner, float* __restrict__ out, int npix) {
    __shared__ float w[4 * NC];
    for (int i = threadIdx.x; i < 4 * NC; i += blockDim.x) w[i] = wg[i];
    __syncthreads();
    int idx = blockIdx.x * blockDim.x + threadIdx.x;
    if (idx >= npix) return;
    if (owner[idx] >= 0) return;   // will be fully overwritten by roi_scatter
    int b = idx >> 14;
    int pix = idx & (HW - 1);
    const float* pr = rgb + (((size_t)b * NC) << 14) + pix;
    const float* pt = tir + (((size_t)b * NC) << 14) + pix;
    float l0 = bg[0], l1 = bg[1];
    #pragma unroll 8
    for (int c = 0; c < NC; ++c) {
        float vr = pr[(size_t)c << 14];
        float vt = pt[(size_t)c << 14];
        l0 = fmaf(w[c],          vr, fmaf(w[NC + c],     vt, l0));
        l1 = fmaf(w[2 * NC + c], vr, fmaf(w[3 * NC + c], vt, l1));
    }
    float m = fmaxf(l0, l1);
    float e0 = expf(l0 - m), e1 = expf(l1 - m);
    float a0 = e0 / (e0 + e1);
    float a1 = 1.0f - a0;
    float* po = out + (((size_t)b * NC) << 14) + pix;
    #pragma unroll 8
    for (int c = 0; c < NC; ++c) {
        float vr = pr[(size_t)c << 14];
        float vt = pt[(size_t)c << 14];
        po[(size_t)c << 14] = fmaf(vr, a0, vt * a1);
    }
}

// ---------------------------------------------------------------------------
// ROI align (bilinear, torchvision semantics) + 2-logit fuse + owner-gated
// scatter. One block per (b, n). 256 threads = 64 point-slots (49 active)
// x 4 channel-groups of 64 channels.
// ---------------------------------------------------------------------------
struct Bilin { int o00, o01, o10, o11; float w00, w01, w10, w11; };

__device__ inline Bilin bilin_setup(float X, float Y) {
    Bilin r;
    bool valid = (X >= -1.0f) && (X <= (float)WW) && (Y >= -1.0f) && (Y <= (float)HH);
    float x = fmaxf(X, 0.0f), y = fmaxf(Y, 0.0f);
    int ix = (int)floorf(x), iy = (int)floorf(y);
    int xl = min(ix, WW - 1), xh = min(ix + 1, WW - 1);
    int yl = min(iy, HH - 1), yh = min(iy + 1, HH - 1);
    float lx = (ix >= WW - 1) ? 0.0f : x - (float)xl;
    float ly = (iy >= HH - 1) ? 0.0f : y - (float)yl;
    float hx = 1.0f - lx, hy = 1.0f - ly;
    r.o00 = (yl << 7) + xl; r.o01 = (yl << 7) + xh;
    r.o10 = (yh << 7) + xl; r.o11 = (yh << 7) + xh;
    float s = valid ? 1.0f : 0.0f;
    r.w00 = hy * hx * s; r.w01 = hy * lx * s;
    r.w10 = ly * hx * s; r.w11 = ly * lx * s;
    return r;
}

__device__ inline float bgather(const float* __restrict__ base, int c, const Bilin& bl) {
    const float* p = base + ((size_t)c << 14);
    return p[bl.o00] * bl.w00 + p[bl.o01] * bl.w01 +
           p[bl.o10] * bl.w10 + p[bl.o11] * bl.w11;
}

__global__ __launch_bounds__(256) void roi_scatter_k(
        const float* __restrict__ rgb, const float* __restrict__ tir,
        const float* __restrict__ a_rgb, const float* __restrict__ a_tir,
        const float* __restrict__ wa, const float* __restrict__ ba,
        const int* __restrict__ owner, float* __restrict__ out, int N) {
    __shared__ float w[4 * NC];
    __shared__ float part0[49][4];
    __shared__ float part1[49][4];
    __shared__ float att0s[49];
    int b = blockIdx.x / N;
    int n = blockIdx.x % N;
    for (int i = threadIdx.x; i < 4 * NC; i += blockDim.x) w[i] = wa[i];

    int p = threadIdx.x & 63;
    int g = threadIdx.x >> 6;
    bool act = (p < 49);
    int px = p % 7, py = p / 7;

    float axr = a_rgb[(size_t)(b * N + n) * 3 + 0];
    float ayr = a_rgb[(size_t)(b * N + n) * 3 + 1];
    float axt = a_tir[(size_t)(b * N + n) * 3 + 0];
    float ayt = a_tir[(size_t)(b * N + n) * 3 + 1];

    // sample point for (py,px): anchor - ROI/2 + (p + 0.5) = anchor - 3 + p
    Bilin br = bilin_setup(axr - 3.0f + (float)px, ayr - 3.0f + (float)py);
    Bilin bt = bilin_setup(axt - 3.0f + (float)px, ayt - 3.0f + (float)py);

    const float* rb = rgb + (((size_t)b * NC) << 14);
    const float* tb = tir + (((size_t)b * NC) << 14);

    __syncthreads();

    int c0 = g * 64;
    if (act) {
        float l0 = 0.f, l1 = 0.f;
        #pragma unroll 4
        for (int cc = 0; cc < 64; ++cc) {
            int c = c0 + cc;
            float vr = bgather(rb, c, br);
            float vt = bgather(tb, c, bt);
            l0 = fmaf(w[c],          vr, fmaf(w[NC + c],     vt, l0));
            l1 = fmaf(w[2 * NC + c], vr, fmaf(w[3 * NC + c], vt, l1));
        }
        part0[p][g] = l0;
        part1[p][g] = l1;
    }
    __syncthreads();
    if (act && g == 0) {
        float L0 = ba[0] + part0[p][0] + part0[p][1] + part0[p][2] + part0[p][3];
        float L1 = ba[1] + part1[p][0] + part1[p][1] + part1[p][2] + part1[p][3];
        float m = fmaxf(L0, L1);
        float e0 = expf(L0 - m), e1 = expf(L1 - m);
        att0s[p] = e0 / (e0 + e1);
    }
    __syncthreads();
    if (!act) return;

    int x0 = (int)truncf(axr - 3.5f); x0 = min(max(x0, 0), WW - ROI);
    int y0 = (int)truncf(ayr - 3.5f); y0 = min(max(y0, 0), HH - ROI);
    int x = x0 + px, y = y0 + py;
    if (owner[((size_t)b << 14) + (y << 7) + x] != n) return;  // later anchor wins

    float a0 = att0s[p], a1 = 1.0f - a0;
    float* po = out + (((size_t)b * NC) << 14) + (y << 7) + x;
    #pragma unroll 4
    for (int cc = 0; cc < 64; ++cc) {
        int c = c0 + cc;
        float vr = bgather(rb, c, br);
        float vt = bgather(tb, c, bt);
        po[(size_t)c << 14] = fmaf(vr, a0, vt * a1);
    }
}

// ---------------------------------------------------------------------------
extern "C" void kernel_launch(void* const* d_in, const int* in_sizes, int n_in,
                              void* d_out, int out_size, void* d_ws, size_t ws_size,
                              hipStream_t stream) {
    const float* frgb = (const float*)d_in[0];
    const float* ftir = (const float*)d_in[1];
    const float* argb = (const float*)d_in[2];
    const float* atir = (const float*)d_in[3];
    const float* wg   = (const float*)d_in[4];
    const float* bgp  = (const float*)d_in[5];
    const float* wa   = (const float*)d_in[6];
    const float* bap  = (const float*)d_in[7];
    float* out = (float*)d_out;

    int B = in_sizes[0] / (NC * HW);       // 8
    int N = in_sizes[2] / (B * 3);         // 128
    int npix = B * HW;                     // 131072

    int* owner = (int*)d_ws;               // B*H*W ints = 512 KB

    init_owner_k<<<(npix + 255) / 256, 256, 0, stream>>>(owner, npix);
    mark_owner_k<<<(B * N * 49 + 255) / 256, 256, 0, stream>>>(argb, owner, B, N);
    fuse_global_k<<<(npix + 255) / 256, 256, 0, stream>>>(frgb, ftir, wg, bgp,
                                                          owner, out, npix);
    roi_scatter_k<<<B * N, 256, 0, stream>>>(frgb, ftir, argb, atir, wa, bap,
                                             owner, out, N);
}

// Round 2
// 281.092 us; speedup vs baseline: 1.7019x; 1.7019x over previous
//
#include <hip/hip_runtime.h>
#include <math.h>

#define ROI 7
#define NC 256          // channels per modality
#define TC 512          // 2*NC concatenated
#define HH 128
#define WW 128
#define HW (HH * WW)    // 16384

// ---------------------------------------------------------------------------
// Owner map: owner[b][y][x] = max anchor index n whose scattered 7x7 patch
// covers (y,x), else -1. Sequential overwrite == "last (max) anchor wins".
// ---------------------------------------------------------------------------
__global__ void init_owner_k(int* __restrict__ owner, int n) {
    int i = blockIdx.x * blockDim.x + threadIdx.x;
    if (i < n) owner[i] = -1;
}

__global__ void mark_owner_k(const float* __restrict__ anchors,
                             int* __restrict__ owner, int B, int N) {
    int i = blockIdx.x * blockDim.x + threadIdx.x;
    int total = B * N * 49;
    if (i >= total) return;
    int p = i % 49;
    int bn = i / 49;
    int n = bn % N;
    int b = bn / N;
    float ax = anchors[(size_t)(b * N + n) * 3 + 0];
    float ay = anchors[(size_t)(b * N + n) * 3 + 1];
    int x0 = (int)truncf(ax - 3.5f); x0 = min(max(x0, 0), WW - ROI);
    int y0 = (int)truncf(ay - 3.5f); y0 = min(max(y0, 0), HH - ROI);
    int x = x0 + (p % 7);
    int y = y0 + (p / 7);
    atomicMax(&owner[((size_t)b << 14) + (y << 7) + x], n);
}

// ---------------------------------------------------------------------------
// Global fusion, single pass over HBM: block = 32 pixels x 512 channels
// staged in 64KB LDS (float4), logits via LDS partial reduce, blend from LDS.
// Writes ALL pixels; roi_scatter_k overwrites owned pixels afterwards.
// ---------------------------------------------------------------------------
__global__ __launch_bounds__(256) void fuse_global_k(
        const float* __restrict__ rgb, const float* __restrict__ tir,
        const float* __restrict__ wg, const float* __restrict__ bg,
        float* __restrict__ out) {
    __shared__ float v[TC][32];          // 64 KB: concatenated [rgb;tir] x 32 px
    __shared__ float w[2 * TC];          // 4 KB
    __shared__ float part0[8][32];
    __shared__ float part1[8][32];
    __shared__ float att[32];

    int tid = threadIdx.x;
    int b = blockIdx.x >> 9;             // 512 blocks per image (16384/32)
    int pix0 = (blockIdx.x & 511) << 5;

    const float* base_r = rgb + (((size_t)b * NC) << 14);
    const float* base_t = tir + (((size_t)b * NC) << 14);

    for (int i = tid; i < 2 * TC; i += 256) w[i] = wg[i];

    // ---- load phase: thread -> (pxq = 4-px group, rr = row), 16 iters float4
    int pxq = (tid & 7) << 2;
    int rr = tid >> 3;                   // 0..31
    #pragma unroll 4
    for (int it = 0; it < 16; ++it) {
        int r = rr + (it << 5);
        const float* src = (r < NC) ? (base_r + ((size_t)r << 14))
                                    : (base_t + ((size_t)(r - NC) << 14));
        float4 val = *reinterpret_cast<const float4*>(src + pix0 + pxq);
        *reinterpret_cast<float4*>(&v[r][pxq]) = val;
    }
    __syncthreads();

    // ---- logits: thread (px, seg) sums 64 rows
    int px = tid & 31, seg = tid >> 5;
    {
        float l0 = 0.f, l1 = 0.f;
        int r0 = seg << 6;
        #pragma unroll 8
        for (int i = 0; i < 64; ++i) {
            float val = v[r0 + i][px];
            l0 = fmaf(w[r0 + i], val, l0);
            l1 = fmaf(w[TC + r0 + i], val, l1);
        }
        part0[seg][px] = l0;
        part1[seg][px] = l1;
    }
    __syncthreads();

    if (tid < 32) {
        float L0 = bg[0], L1 = bg[1];
        #pragma unroll
        for (int s = 0; s < 8; ++s) { L0 += part0[s][tid]; L1 += part1[s][tid]; }
        float m = fmaxf(L0, L1);
        float e0 = expf(L0 - m), e1 = expf(L1 - m);
        att[tid] = e0 / (e0 + e1);
    }
    __syncthreads();

    // ---- blend + store: thread -> (pxq, cg = 8 channels), float4 out
    int cg = tid >> 3;
    float4 a4 = *reinterpret_cast<float4*>(&att[pxq]);
    float* ob = out + (((size_t)b * NC) << 14) + pix0 + pxq;
    #pragma unroll
    for (int i = 0; i < 8; ++i) {
        int c = (cg << 3) + i;
        float4 vr = *reinterpret_cast<float4*>(&v[c][pxq]);
        float4 vt = *reinterpret_cast<float4*>(&v[NC + c][pxq]);
        float4 o;
        o.x = fmaf(a4.x, vr.x - vt.x, vt.x);
        o.y = fmaf(a4.y, vr.y - vt.y, vt.y);
        o.z = fmaf(a4.z, vr.z - vt.z, vt.z);
        o.w = fmaf(a4.w, vr.w - vt.w, vt.w);
        *reinterpret_cast<float4*>(ob + ((size_t)c << 14)) = o;
    }
}

// ---------------------------------------------------------------------------
// ROI align + fuse + owner-gated scatter, ONE gather pass: values held in
// registers across the logit reduction. 512 threads = 64 point-slots
// (49 active) x 8 channel-groups of 32 channels.
// ---------------------------------------------------------------------------
struct Bilin { int o00, o01, o10, o11; float w00, w01, w10, w11; };

__device__ inline Bilin bilin_setup(float X, float Y) {
    Bilin r;
    bool valid = (X >= -1.0f) && (X <= (float)WW) && (Y >= -1.0f) && (Y <= (float)HH);
    float x = fmaxf(X, 0.0f), y = fmaxf(Y, 0.0f);
    int ix = (int)floorf(x), iy = (int)floorf(y);
    int xl = min(ix, WW - 1), xh = min(ix + 1, WW - 1);
    int yl = min(iy, HH - 1), yh = min(iy + 1, HH - 1);
    float lx = (ix >= WW - 1) ? 0.0f : x - (float)xl;
    float ly = (iy >= HH - 1) ? 0.0f : y - (float)yl;
    float hx = 1.0f - lx, hy = 1.0f - ly;
    r.o00 = (yl << 7) + xl; r.o01 = (yl << 7) + xh;
    r.o10 = (yh << 7) + xl; r.o11 = (yh << 7) + xh;
    float s = valid ? 1.0f : 0.0f;
    r.w00 = hy * hx * s; r.w01 = hy * lx * s;
    r.w10 = ly * hx * s; r.w11 = ly * lx * s;
    return r;
}

__device__ inline float bgather(const float* __restrict__ base, int c, const Bilin& bl) {
    const float* p = base + ((size_t)c << 14);
    return p[bl.o00] * bl.w00 + p[bl.o01] * bl.w01 +
           p[bl.o10] * bl.w10 + p[bl.o11] * bl.w11;
}

__global__ __launch_bounds__(512) void roi_scatter_k(
        const float* __restrict__ rgb, const float* __restrict__ tir,
        const float* __restrict__ a_rgb, const float* __restrict__ a_tir,
        const float* __restrict__ wa, const float* __restrict__ ba,
        const int* __restrict__ owner, float* __restrict__ out, int N) {
    __shared__ float w[2 * TC];
    __shared__ float part0[64][9];       // +1 pad: conflict-free partial store
    __shared__ float part1[64][9];
    __shared__ float att0s[64];

    int b = blockIdx.x / N;
    int n = blockIdx.x % N;
    for (int i = threadIdx.x; i < 2 * TC; i += 512) w[i] = wa[i];

    int p = threadIdx.x & 63;
    int g = threadIdx.x >> 6;            // 0..7 -> 32 channels each
    bool act = (p < 49);
    int px = p % 7, py = p / 7;

    float axr = a_rgb[(size_t)(b * N + n) * 3 + 0];
    float ayr = a_rgb[(size_t)(b * N + n) * 3 + 1];
    float axt = a_tir[(size_t)(b * N + n) * 3 + 0];
    float ayt = a_tir[(size_t)(b * N + n) * 3 + 1];

    // sample point for (py,px): anchor - ROI/2 + (p + 0.5) = anchor - 3 + p
    Bilin br = bilin_setup(axr - 3.0f + (float)px, ayr - 3.0f + (float)py);
    Bilin bt = bilin_setup(axt - 3.0f + (float)px, ayt - 3.0f + (float)py);

    const float* rb = rgb + (((size_t)b * NC) << 14);
    const float* tb = tir + (((size_t)b * NC) << 14);

    __syncthreads();

    int c0 = g << 5;
    float vr[32], vt[32];
    if (act) {
        float l0 = 0.f, l1 = 0.f;
        #pragma unroll
        for (int i = 0; i < 32; ++i) {
            int c = c0 + i;
            vr[i] = bgather(rb, c, br);
            vt[i] = bgather(tb, c, bt);
            l0 = fmaf(w[c],          vr[i], fmaf(w[NC + c],     vt[i], l0));
            l1 = fmaf(w[2 * NC + c], vr[i], fmaf(w[3 * NC + c], vt[i], l1));
        }
        part0[p][g] = l0;
        part1[p][g] = l1;
    }
    __syncthreads();
    if (act && g == 0) {
        float L0 = ba[0], L1 = ba[1];
        #pragma unroll
        for (int s = 0; s < 8; ++s) { L0 += part0[p][s]; L1 += part1[p][s]; }
        float m = fmaxf(L0, L1);
        float e0 = expf(L0 - m), e1 = expf(L1 - m);
        att0s[p] = e0 / (e0 + e1);
    }
    __syncthreads();
    if (!act) return;

    int x0 = (int)truncf(axr - 3.5f); x0 = min(max(x0, 0), WW - ROI);
    int y0 = (int)truncf(ayr - 3.5f); y0 = min(max(y0, 0), HH - ROI);
    int x = x0 + px, y = y0 + py;
    if (owner[((size_t)b << 14) + (y << 7) + x] != n) return;  // later anchor wins

    float a0 = att0s[p];
    float* po = out + (((size_t)b * NC) << 14) + (y << 7) + x;
    #pragma unroll
    for (int i = 0; i < 32; ++i) {
        int c = c0 + i;
        po[(size_t)c << 14] = fmaf(a0, vr[i] - vt[i], vt[i]);
    }
}

// ---------------------------------------------------------------------------
extern "C" void kernel_launch(void* const* d_in, const int* in_sizes, int n_in,
                              void* d_out, int out_size, void* d_ws, size_t ws_size,
                              hipStream_t stream) {
    const float* frgb = (const float*)d_in[0];
    const float* ftir = (const float*)d_in[1];
    const float* argb = (const float*)d_in[2];
    const float* atir = (const float*)d_in[3];
    const float* wg   = (const float*)d_in[4];
    const float* bgp  = (const float*)d_in[5];
    const float* wa   = (const float*)d_in[6];
    const float* bap  = (const float*)d_in[7];
    float* out = (float*)d_out;

    int B = in_sizes[0] / (NC * HW);       // 8
    int N = in_sizes[2] / (B * 3);         // 128
    int npix = B * HW;                     // 131072

    int* owner = (int*)d_ws;               // B*H*W ints = 512 KB

    init_owner_k<<<(npix + 255) / 256, 256, 0, stream>>>(owner, npix);
    mark_owner_k<<<(B * N * 49 + 255) / 256, 256, 0, stream>>>(argb, owner, B, N);
    fuse_global_k<<<npix / 32, 256, 0, stream>>>(frgb, ftir, wg, bgp, out);
    roi_scatter_k<<<B * N, 512, 0, stream>>>(frgb, ftir, argb, atir, wa, bap,
                                             owner, out, N);
}

// Round 4
// 242.391 us; speedup vs baseline: 1.9736x; 1.1597x over previous
//
#include <hip/hip_runtime.h>
#include <math.h>

#define ROI 7
#define NC 256          // channels per modality
#define TC 512          // 2*NC concatenated
#define HH 128
#define WW 128
#define HW (HH * WW)    // 16384

typedef float floatx4 __attribute__((ext_vector_type(4)));

// ---------------------------------------------------------------------------
// Owner map: owner[b][y][x] = max anchor index n whose scattered 7x7 patch
// covers (y,x), else -1. Sequential overwrite == "last (max) anchor wins".
// ---------------------------------------------------------------------------
__global__ void init_owner_k(int* __restrict__ owner, int n) {
    int i = blockIdx.x * blockDim.x + threadIdx.x;
    if (i < n) owner[i] = -1;
}

__global__ void mark_owner_k(const float* __restrict__ anchors,
                             int* __restrict__ owner, int B, int N) {
    int i = blockIdx.x * blockDim.x + threadIdx.x;
    int total = B * N * 49;
    if (i >= total) return;
    int p = i % 49;
    int bn = i / 49;
    int n = bn % N;
    int b = bn / N;
    float ax = anchors[(size_t)(b * N + n) * 3 + 0];
    float ay = anchors[(size_t)(b * N + n) * 3 + 1];
    int x0 = (int)truncf(ax - 3.5f); x0 = min(max(x0, 0), WW - ROI);
    int y0 = (int)truncf(ay - 3.5f); y0 = min(max(y0, 0), HH - ROI);
    int x = x0 + (p % 7);
    int y = y0 + (p / 7);
    atomicMax(&owner[((size_t)b << 14) + (y << 7) + x], n);
}

// ---------------------------------------------------------------------------
// Global fusion, single HBM pass: block = 16 pixels x 512 channels in 32KB
// LDS (4 blocks/CU). Fully-owned 4-px quads are skipped (roi overwrites
// them). Output stores are nontemporal to keep features resident in L3.
// ---------------------------------------------------------------------------
__global__ __launch_bounds__(256) void fuse_global_k(
        const float* __restrict__ rgb, const float* __restrict__ tir,
        const float* __restrict__ wg, const float* __restrict__ bg,
        const int* __restrict__ owner, float* __restrict__ out) {
    __shared__ float v[TC][16];          // 32 KB
    __shared__ float w[2 * TC];          // 4 KB (1024 floats)
    __shared__ float part0[16][16];
    __shared__ float part1[16][16];
    __shared__ float att[16];
    __shared__ int   sskip[4];

    int tid = threadIdx.x;
    int b = blockIdx.x >> 10;            // 1024 blocks per image (16384/16)
    int pix0 = (blockIdx.x & 1023) << 4;

    const float* base_r = rgb + (((size_t)b * NC) << 14);
    const float* base_t = tir + (((size_t)b * NC) << 14);

    if (tid < 4) {
        int4 o4 = *reinterpret_cast<const int4*>(
            owner + (((size_t)b << 14) + pix0 + tid * 4));
        sskip[tid] = (o4.x >= 0 && o4.y >= 0 && o4.z >= 0 && o4.w >= 0);
    }
    for (int i = tid; i < 2 * TC; i += 256) w[i] = wg[i];
    __syncthreads();

    // ---- load: thread -> (quad q, row r0), 8 iters of float4
    int q = tid & 3;
    int r0 = tid >> 2;                   // 0..63
    bool skipq = sskip[q];
    if (!skipq) {
        #pragma unroll
        for (int it = 0; it < 8; ++it) {
            int r = r0 + (it << 6);
            const float* src = (r < NC) ? (base_r + ((size_t)r << 14))
                                        : (base_t + ((size_t)(r - NC) << 14));
            float4 val = *reinterpret_cast<const float4*>(src + pix0 + (q << 2));
            *reinterpret_cast<float4*>(&v[r][q << 2]) = val;
        }
    }
    __syncthreads();

    // ---- logits: thread (px, seg) sums 32 rows
    {
        int px = tid & 15, seg = tid >> 4;
        float l0 = 0.f, l1 = 0.f;
        int rb = seg << 5;
        #pragma unroll 8
        for (int i = 0; i < 32; ++i) {
            float val = v[rb + i][px];
            l0 = fmaf(w[rb + i], val, l0);
            l1 = fmaf(w[TC + rb + i], val, l1);
        }
        part0[seg][px] = l0;
        part1[seg][px] = l1;
    }
    __syncthreads();

    if (tid < 16) {
        float L0 = bg[0], L1 = bg[1];
        #pragma unroll
        for (int s = 0; s < 16; ++s) { L0 += part0[s][tid]; L1 += part1[s][tid]; }
        float m = fmaxf(L0, L1);
        float e0 = expf(L0 - m), e1 = expf(L1 - m);
        att[tid] = e0 / (e0 + e1);
    }
    __syncthreads();

    // ---- blend + nontemporal store: thread -> (quad q, 4 channels)
    if (skipq) return;
    int cb = tid >> 2;                   // 0..63
    float4 a4 = *reinterpret_cast<float4*>(&att[q << 2]);
    float* ob = out + (((size_t)b * NC) << 14) + pix0 + (q << 2);
    #pragma unroll
    for (int i = 0; i < 4; ++i) {
        int c = cb + (i << 6);
        float4 vr = *reinterpret_cast<float4*>(&v[c][q << 2]);
        float4 vt = *reinterpret_cast<float4*>(&v[NC + c][q << 2]);
        floatx4 o;
        o.x = fmaf(a4.x, vr.x - vt.x, vt.x);
        o.y = fmaf(a4.y, vr.y - vt.y, vt.y);
        o.z = fmaf(a4.z, vr.z - vt.z, vt.z);
        o.w = fmaf(a4.w, vr.w - vt.w, vt.w);
        __builtin_nontemporal_store(o,
            reinterpret_cast<floatx4*>(ob + ((size_t)c << 14)));
    }
}

// ---------------------------------------------------------------------------
// ROI align + fuse + scatter. Per-point independence: a point that loses the
// owner race does NO gathers/logits (its softmax is private to the point).
// 512 threads = 64 point-slots (49 active) x 8 groups of 32 channels; values
// kept in registers across logit reduce -> single gather pass.
// ---------------------------------------------------------------------------
struct Bilin { int o00, o01, o10, o11; float w00, w01, w10, w11; };

__device__ inline Bilin bilin_setup(float X, float Y) {
    Bilin r;
    bool valid = (X >= -1.0f) && (X <= (float)WW) && (Y >= -1.0f) && (Y <= (float)HH);
    float x = fmaxf(X, 0.0f), y = fmaxf(Y, 0.0f);
    int ix = (int)floorf(x), iy = (int)floorf(y);
    int xl = min(ix, WW - 1), xh = min(ix + 1, WW - 1);
    int yl = min(iy, HH - 1), yh = min(iy + 1, HH - 1);
    float lx = (ix >= WW - 1) ? 0.0f : x - (float)xl;
    float ly = (iy >= HH - 1) ? 0.0f : y - (float)yl;
    float hx = 1.0f - lx, hy = 1.0f - ly;
    r.o00 = (yl << 7) + xl; r.o01 = (yl << 7) + xh;
    r.o10 = (yh << 7) + xl; r.o11 = (yh << 7) + xh;
    float s = valid ? 1.0f : 0.0f;
    r.w00 = hy * hx * s; r.w01 = hy * lx * s;
    r.w10 = ly * hx * s; r.w11 = ly * lx * s;
    return r;
}

__device__ inline float bgather(const float* __restrict__ base, int c, const Bilin& bl) {
    const float* p = base + ((size_t)c << 14);
    return p[bl.o00] * bl.w00 + p[bl.o01] * bl.w01 +
           p[bl.o10] * bl.w10 + p[bl.o11] * bl.w11;
}

__global__ __launch_bounds__(512) void roi_scatter_k(
        const float* __restrict__ rgb, const float* __restrict__ tir,
        const float* __restrict__ a_rgb, const float* __restrict__ a_tir,
        const float* __restrict__ wa, const float* __restrict__ ba,
        const int* __restrict__ owner, float* __restrict__ out, int N, int B) {
    __shared__ float w[2 * TC];
    __shared__ float part0[64][9];
    __shared__ float part1[64][9];
    __shared__ float att0s[64];

    int bid = blockIdx.x;
    int b = (B - 1) - bid / N;           // reverse image order: L3 warm from fuse
    int n = bid % N;
    for (int i = threadIdx.x; i < 2 * TC; i += 512) w[i] = wa[i];

    int p = threadIdx.x & 63;
    int g = threadIdx.x >> 6;            // 0..7 -> 32 channels each
    int px = p % 7, py = p / 7;

    float axr = a_rgb[(size_t)(b * N + n) * 3 + 0];
    float ayr = a_rgb[(size_t)(b * N + n) * 3 + 1];
    float axt = a_tir[(size_t)(b * N + n) * 3 + 0];
    float ayt = a_tir[(size_t)(b * N + n) * 3 + 1];

    int x0 = (int)truncf(axr - 3.5f); x0 = min(max(x0, 0), WW - ROI);
    int y0 = (int)truncf(ayr - 3.5f); y0 = min(max(y0, 0), HH - ROI);
    int x = x0 + px, y = y0 + py;

    // pre-gate on ownership: losing points skip ALL gathers + logits
    bool act = (p < 49);
    if (act) act = (owner[((size_t)b << 14) + (y << 7) + x] == n);

    Bilin br = bilin_setup(axr - 3.0f + (float)px, ayr - 3.0f + (float)py);
    Bilin bt = bilin_setup(axt - 3.0f + (float)px, ayt - 3.0f + (float)py);

    const float* rb = rgb + (((size_t)b * NC) << 14);
    const float* tb = tir + (((size_t)b * NC) << 14);

    __syncthreads();

    int c0 = g << 5;
    float vr[32], vt[32];
    if (act) {
        float l0 = 0.f, l1 = 0.f;
        #pragma unroll
        for (int i = 0; i < 32; ++i) {
            int c = c0 + i;
            vr[i] = bgather(rb, c, br);
            vt[i] = bgather(tb, c, bt);
            l0 = fmaf(w[c],          vr[i], fmaf(w[NC + c],     vt[i], l0));
            l1 = fmaf(w[2 * NC + c], vr[i], fmaf(w[3 * NC + c], vt[i], l1));
        }
        part0[p][g] = l0;
        part1[p][g] = l1;
    }
    __syncthreads();
    if (g == 0 && p < 49) {
        float L0 = ba[0], L1 = ba[1];
        #pragma unroll
        for (int s = 0; s < 8; ++s) { L0 += part0[p][s]; L1 += part1[p][s]; }
        float m = fmaxf(L0, L1);
        float e0 = expf(L0 - m), e1 = expf(L1 - m);
        att0s[p] = e0 / (e0 + e1);
    }
    __syncthreads();
    if (!act) return;

    float a0 = att0s[p];
    float* po = out + (((size_t)b * NC) << 14) + (y << 7) + x;
    #pragma unroll
    for (int i = 0; i < 32; ++i) {
        int c = c0 + i;
        po[(size_t)c << 14] = fmaf(a0, vr[i] - vt[i], vt[i]);
    }
}

// ---------------------------------------------------------------------------
extern "C" void kernel_launch(void* const* d_in, const int* in_sizes, int n_in,
                              void* d_out, int out_size, void* d_ws, size_t ws_size,
                              hipStream_t stream) {
    const float* frgb = (const float*)d_in[0];
    const float* ftir = (const float*)d_in[1];
    const float* argb = (const float*)d_in[2];
    const float* atir = (const float*)d_in[3];
    const float* wg   = (const float*)d_in[4];
    const float* bgp  = (const float*)d_in[5];
    const float* wa   = (const float*)d_in[6];
    const float* bap  = (const float*)d_in[7];
    float* out = (float*)d_out;

    int B = in_sizes[0] / (NC * HW);       // 8
    int N = in_sizes[2] / (B * 3);         // 128
    int npix = B * HW;                     // 131072

    int* owner = (int*)d_ws;               // B*H*W ints = 512 KB

    init_owner_k<<<(npix + 255) / 256, 256, 0, stream>>>(owner, npix);
    mark_owner_k<<<(B * N * 49 + 255) / 256, 256, 0, stream>>>(argb, owner, B, N);
    fuse_global_k<<<npix / 16, 256, 0, stream>>>(frgb, ftir, wg, bgp, owner, out);
    roi_scatter_k<<<B * N, 512, 0, stream>>>(frgb, ftir, argb, atir, wa, bap,
                                             owner, out, N, B);
}

// Round 5
// 223.564 us; speedup vs baseline: 2.1398x; 1.0842x over previous
//
#include <hip/hip_runtime.h>
#include <math.h>

#define ROI 7
#define NC 256          // channels per modality
#define TC 512          // 2*NC concatenated
#define HH 128
#define WW 128
#define HW (HH * WW)    // 16384

// ---------------------------------------------------------------------------
// Owner map: owner[b][y][x] = max anchor index n whose scattered 7x7 patch
// covers (y,x), else -1. Sequential overwrite == "last (max) anchor wins".
// ---------------------------------------------------------------------------
__global__ void init_owner_k(int* __restrict__ owner, int n) {
    int i = blockIdx.x * blockDim.x + threadIdx.x;
    if (i < n) owner[i] = -1;
}

__global__ void mark_owner_k(const float* __restrict__ anchors,
                             int* __restrict__ owner, int B, int N) {
    int i = blockIdx.x * blockDim.x + threadIdx.x;
    int total = B * N * 49;
    if (i >= total) return;
    int p = i % 49;
    int bn = i / 49;
    int n = bn % N;
    int b = bn / N;
    float ax = anchors[(size_t)(b * N + n) * 3 + 0];
    float ay = anchors[(size_t)(b * N + n) * 3 + 1];
    int x0 = (int)truncf(ax - 3.5f); x0 = min(max(x0, 0), WW - ROI);
    int y0 = (int)truncf(ay - 3.5f); y0 = min(max(y0, 0), HH - ROI);
    int x = x0 + (p % 7);
    int y = y0 + (p / 7);
    atomicMax(&owner[((size_t)b << 14) + (y << 7) + x], n);
}

// ---------------------------------------------------------------------------
// Global fusion, register-resident single pass. Block = 64 pixels x 8
// channel-groups (512 threads). Thread holds 32 rgb + 32 tir values in
// VGPRs across the logit reduce; loads/stores are lane=pixel coalesced
// (256B per wave-instr). LDS only for weights + logit partials (~9 KB).
// Owned pixels (overwritten by roi_scatter later) skip everything.
// ---------------------------------------------------------------------------
__global__ __launch_bounds__(512, 4) void fuse_global_k(
        const float* __restrict__ rgb, const float* __restrict__ tir,
        const float* __restrict__ wg, const float* __restrict__ bg,
        const int* __restrict__ owner, float* __restrict__ out) {
    __shared__ float w[2 * TC];          // 4 KB
    __shared__ float part0[64][9];       // +1 pad
    __shared__ float part1[64][9];
    __shared__ float att[64];

    int tid = threadIdx.x;
    int px = tid & 63;
    int g  = tid >> 6;                   // 0..7 -> 32 channels each
    int b = blockIdx.x >> 8;             // 256 blocks per image (16384/64)
    int pix = ((blockIdx.x & 255) << 6) + px;

    for (int i = tid; i < 2 * TC; i += 512) w[i] = wg[i];

    bool act = owner[((size_t)b << 14) + pix] < 0;   // owned -> roi overwrites

    const float* pr = rgb + (((size_t)b * NC) << 14) + pix;
    const float* pt = tir + (((size_t)b * NC) << 14) + pix;
    int c0 = g << 5;

    __syncthreads();

    float vr[32], vt[32];
    if (act) {
        float l0 = 0.f, l1 = 0.f;
        #pragma unroll
        for (int i = 0; i < 32; ++i) {
            int c = c0 + i;
            vr[i] = pr[(size_t)c << 14];
            vt[i] = pt[(size_t)c << 14];
            l0 = fmaf(w[c],          vr[i], fmaf(w[NC + c],     vt[i], l0));
            l1 = fmaf(w[2 * NC + c], vr[i], fmaf(w[3 * NC + c], vt[i], l1));
        }
        part0[px][g] = l0;
        part1[px][g] = l1;
    }
    __syncthreads();
    if (g == 0 && act) {
        float L0 = bg[0], L1 = bg[1];
        #pragma unroll
        for (int s = 0; s < 8; ++s) { L0 += part0[px][s]; L1 += part1[px][s]; }
        float m = fmaxf(L0, L1);
        float e0 = expf(L0 - m), e1 = expf(L1 - m);
        att[px] = e0 / (e0 + e1);
    }
    __syncthreads();
    if (!act) return;

    float a0 = att[px];
    float* po = out + (((size_t)b * NC) << 14) + pix;
    #pragma unroll
    for (int i = 0; i < 32; ++i) {
        int c = c0 + i;
        po[(size_t)c << 14] = fmaf(a0, vr[i] - vt[i], vt[i]);
    }
}

// ---------------------------------------------------------------------------
// ROI align + fuse + scatter. Points that lose the owner race do NO work.
// 512 threads = 64 point-slots (49 active) x 8 groups of 32 channels; values
// kept in registers across logit reduce -> single gather pass.
// ---------------------------------------------------------------------------
struct Bilin { int o00, o01, o10, o11; float w00, w01, w10, w11; };

__device__ inline Bilin bilin_setup(float X, float Y) {
    Bilin r;
    bool valid = (X >= -1.0f) && (X <= (float)WW) && (Y >= -1.0f) && (Y <= (float)HH);
    float x = fmaxf(X, 0.0f), y = fmaxf(Y, 0.0f);
    int ix = (int)floorf(x), iy = (int)floorf(y);
    int xl = min(ix, WW - 1), xh = min(ix + 1, WW - 1);
    int yl = min(iy, HH - 1), yh = min(iy + 1, HH - 1);
    float lx = (ix >= WW - 1) ? 0.0f : x - (float)xl;
    float ly = (iy >= HH - 1) ? 0.0f : y - (float)yl;
    float hx = 1.0f - lx, hy = 1.0f - ly;
    r.o00 = (yl << 7) + xl; r.o01 = (yl << 7) + xh;
    r.o10 = (yh << 7) + xl; r.o11 = (yh << 7) + xh;
    float s = valid ? 1.0f : 0.0f;
    r.w00 = hy * hx * s; r.w01 = hy * lx * s;
    r.w10 = ly * hx * s; r.w11 = ly * lx * s;
    return r;
}

__device__ inline float bgather(const float* __restrict__ base, int c, const Bilin& bl) {
    const float* p = base + ((size_t)c << 14);
    return p[bl.o00] * bl.w00 + p[bl.o01] * bl.w01 +
           p[bl.o10] * bl.w10 + p[bl.o11] * bl.w11;
}

__global__ __launch_bounds__(512) void roi_scatter_k(
        const float* __restrict__ rgb, const float* __restrict__ tir,
        const float* __restrict__ a_rgb, const float* __restrict__ a_tir,
        const float* __restrict__ wa, const float* __restrict__ ba,
        const int* __restrict__ owner, float* __restrict__ out, int N, int B) {
    __shared__ float w[2 * TC];
    __shared__ float part0[64][9];
    __shared__ float part1[64][9];
    __shared__ float att0s[64];

    int bid = blockIdx.x;
    int b = (B - 1) - bid / N;           // reverse image order: L3 warm from fuse
    int n = bid % N;
    for (int i = threadIdx.x; i < 2 * TC; i += 512) w[i] = wa[i];

    int p = threadIdx.x & 63;
    int g = threadIdx.x >> 6;            // 0..7 -> 32 channels each
    int px = p % 7, py = p / 7;

    float axr = a_rgb[(size_t)(b * N + n) * 3 + 0];
    float ayr = a_rgb[(size_t)(b * N + n) * 3 + 1];
    float axt = a_tir[(size_t)(b * N + n) * 3 + 0];
    float ayt = a_tir[(size_t)(b * N + n) * 3 + 1];

    int x0 = (int)truncf(axr - 3.5f); x0 = min(max(x0, 0), WW - ROI);
    int y0 = (int)truncf(ayr - 3.5f); y0 = min(max(y0, 0), HH - ROI);
    int x = x0 + px, y = y0 + py;

    // pre-gate on ownership: losing points skip ALL gathers + logits
    bool act = (p < 49);
    if (act) act = (owner[((size_t)b << 14) + (y << 7) + x] == n);

    Bilin br = bilin_setup(axr - 3.0f + (float)px, ayr - 3.0f + (float)py);
    Bilin bt = bilin_setup(axt - 3.0f + (float)px, ayt - 3.0f + (float)py);

    const float* rb = rgb + (((size_t)b * NC) << 14);
    const float* tb = tir + (((size_t)b * NC) << 14);

    __syncthreads();

    int c0 = g << 5;
    float vr[32], vt[32];
    if (act) {
        float l0 = 0.f, l1 = 0.f;
        #pragma unroll
        for (int i = 0; i < 32; ++i) {
            int c = c0 + i;
            vr[i] = bgather(rb, c, br);
            vt[i] = bgather(tb, c, bt);
            l0 = fmaf(w[c],          vr[i], fmaf(w[NC + c],     vt[i], l0));
            l1 = fmaf(w[2 * NC + c], vr[i], fmaf(w[3 * NC + c], vt[i], l1));
        }
        part0[p][g] = l0;
        part1[p][g] = l1;
    }
    __syncthreads();
    if (g == 0 && p < 49) {
        float L0 = ba[0], L1 = ba[1];
        #pragma unroll
        for (int s = 0; s < 8; ++s) { L0 += part0[p][s]; L1 += part1[p][s]; }
        float m = fmaxf(L0, L1);
        float e0 = expf(L0 - m), e1 = expf(L1 - m);
        att0s[p] = e0 / (e0 + e1);
    }
    __syncthreads();
    if (!act) return;

    float a0 = att0s[p];
    float* po = out + (((size_t)b * NC) << 14) + (y << 7) + x;
    #pragma unroll
    for (int i = 0; i < 32; ++i) {
        int c = c0 + i;
        po[(size_t)c << 14] = fmaf(a0, vr[i] - vt[i], vt[i]);
    }
}

// ---------------------------------------------------------------------------
extern "C" void kernel_launch(void* const* d_in, const int* in_sizes, int n_in,
                              void* d_out, int out_size, void* d_ws, size_t ws_size,
                              hipStream_t stream) {
    const float* frgb = (const float*)d_in[0];
    const float* ftir = (const float*)d_in[1];
    const float* argb = (const float*)d_in[2];
    const float* atir = (const float*)d_in[3];
    const float* wg   = (const float*)d_in[4];
    const float* bgp  = (const float*)d_in[5];
    const float* wa   = (const float*)d_in[6];
    const float* bap  = (const float*)d_in[7];
    float* out = (float*)d_out;

    int B = in_sizes[0] / (NC * HW);       // 8
    int N = in_sizes[2] / (B * 3);         // 128
    int npix = B * HW;                     // 131072

    int* owner = (int*)d_ws;               // B*H*W ints = 512 KB

    init_owner_k<<<(npix + 255) / 256, 256, 0, stream>>>(owner, npix);
    mark_owner_k<<<(B * N * 49 + 255) / 256, 256, 0, stream>>>(argb, owner, B, N);
    fuse_global_k<<<npix / 64, 512, 0, stream>>>(frgb, ftir, wg, bgp, owner, out);
    roi_scatter_k<<<B * N, 512, 0, stream>>>(frgb, ftir, argb, atir, wa, bap,
                                             owner, out, N, B);
}

// Round 6
// 196.140 us; speedup vs baseline: 2.4390x; 1.1398x over previous
//
#include <hip/hip_runtime.h>
#include <math.h>

#define ROI 7
#define NC 256          // channels per modality
#define TC 512          // 2*NC concatenated
#define HH 128
#define WW 128
#define HW (HH * WW)    // 16384

// ---------------------------------------------------------------------------
// Owner map: owner[b][y][x] = max anchor index n whose scattered 7x7 patch
// covers (y,x), else -1. Sequential overwrite == "last (max) anchor wins".
// ---------------------------------------------------------------------------
__global__ void init_owner_k(int* __restrict__ owner, int n) {
    int i = blockIdx.x * blockDim.x + threadIdx.x;
    if (i < n) owner[i] = -1;
}

__global__ void mark_owner_k(const float* __restrict__ anchors,
                             int* __restrict__ owner, int B, int N) {
    int i = blockIdx.x * blockDim.x + threadIdx.x;
    int total = B * N * 49;
    if (i >= total) return;
    int p = i % 49;
    int bn = i / 49;
    int n = bn % N;
    int b = bn / N;
    float ax = anchors[(size_t)(b * N + n) * 3 + 0];
    float ay = anchors[(size_t)(b * N + n) * 3 + 1];
    int x0 = (int)truncf(ax - 3.5f); x0 = min(max(x0, 0), WW - ROI);
    int y0 = (int)truncf(ay - 3.5f); y0 = min(max(y0, 0), HH - ROI);
    int x = x0 + (p % 7);
    int y = y0 + (p / 7);
    atomicMax(&owner[((size_t)b << 14) + (y << 7) + x], n);
}

// ---------------------------------------------------------------------------
struct Bilin { int o00, o01, o10, o11; float w00, w01, w10, w11; };

__device__ inline Bilin bilin_setup(float X, float Y) {
    Bilin r;
    bool valid = (X >= -1.0f) && (X <= (float)WW) && (Y >= -1.0f) && (Y <= (float)HH);
    float x = fmaxf(X, 0.0f), y = fmaxf(Y, 0.0f);
    int ix = (int)floorf(x), iy = (int)floorf(y);
    int xl = min(ix, WW - 1), xh = min(ix + 1, WW - 1);
    int yl = min(iy, HH - 1), yh = min(iy + 1, HH - 1);
    float lx = (ix >= WW - 1) ? 0.0f : x - (float)xl;
    float ly = (iy >= HH - 1) ? 0.0f : y - (float)yl;
    float hx = 1.0f - lx, hy = 1.0f - ly;
    r.o00 = (yl << 7) + xl; r.o01 = (yl << 7) + xh;
    r.o10 = (yh << 7) + xl; r.o11 = (yh << 7) + xh;
    float s = valid ? 1.0f : 0.0f;
    r.w00 = hy * hx * s; r.w01 = hy * lx * s;
    r.w10 = ly * hx * s; r.w11 = ly * lx * s;
    return r;
}

__device__ inline float bgather(const float* __restrict__ base, int c, const Bilin& bl) {
    const float* p = base + ((size_t)c << 14);
    return p[bl.o00] * bl.w00 + p[bl.o01] * bl.w01 +
           p[bl.o10] * bl.w10 + p[bl.o11] * bl.w11;
}

// ---------------------------------------------------------------------------
// Merged kernel: fuse-blocks and roi-blocks in ONE launch (independent work:
// fuse writes unowned pixels, roi writes owned pixels; both only read
// features + owner). Interleave 1 roi : 2 fuse so each CU hosts a mix --
// fuse's BW-bound streaming fills roi's gather-latency stalls, and roi's
// reads hit L3 lines fuse just streamed.
// ---------------------------------------------------------------------------
__global__ __launch_bounds__(512) void fused_k(
        const float* __restrict__ rgb, const float* __restrict__ tir,
        const float* __restrict__ a_rgb, const float* __restrict__ a_tir,
        const float* __restrict__ wg, const float* __restrict__ bg,
        const float* __restrict__ wa, const float* __restrict__ ba,
        const int* __restrict__ owner, float* __restrict__ out,
        int N, int nRoi, int nFuse) {
    __shared__ float w[2 * TC];
    __shared__ float part0[64][9];
    __shared__ float part1[64][9];
    __shared__ float att[64];

    int bid = blockIdx.x;
    int tid = threadIdx.x;

    bool isRoi;
    int idx;
    if (nFuse == 2 * nRoi) {             // interleaved mapping (1 roi : 2 fuse)
        int q = bid / 3, r = bid - 3 * q;
        isRoi = (r == 0);
        idx = isRoi ? q : (bid - q - 1);
    } else {                              // generic fallback
        isRoi = (bid < nRoi);
        idx = isRoi ? bid : (bid - nRoi);
    }

    int p  = tid & 63;
    int g  = tid >> 6;                   // 0..7 -> 32 channels each
    int c0 = g << 5;

    if (isRoi) {
        // ================= ROI align + fuse + owner-gated scatter =========
        int b = idx / N, n = idx % N;
        for (int i = tid; i < 2 * TC; i += 512) w[i] = wa[i];

        int px = p % 7, py = p / 7;

        float axr = a_rgb[(size_t)(b * N + n) * 3 + 0];
        float ayr = a_rgb[(size_t)(b * N + n) * 3 + 1];
        float axt = a_tir[(size_t)(b * N + n) * 3 + 0];
        float ayt = a_tir[(size_t)(b * N + n) * 3 + 1];

        int x0 = (int)truncf(axr - 3.5f); x0 = min(max(x0, 0), WW - ROI);
        int y0 = (int)truncf(ayr - 3.5f); y0 = min(max(y0, 0), HH - ROI);
        int x = x0 + px, y = y0 + py;

        bool act = (p < 49);
        if (act) act = (owner[((size_t)b << 14) + (y << 7) + x] == n);

        Bilin br = bilin_setup(axr - 3.0f + (float)px, ayr - 3.0f + (float)py);
        Bilin bt = bilin_setup(axt - 3.0f + (float)px, ayt - 3.0f + (float)py);

        const float* rb = rgb + (((size_t)b * NC) << 14);
        const float* tb = tir + (((size_t)b * NC) << 14);

        __syncthreads();

        float vr[32], vt[32];
        if (act) {
            float l0 = 0.f, l1 = 0.f;
            #pragma unroll
            for (int i = 0; i < 32; ++i) {
                int c = c0 + i;
                vr[i] = bgather(rb, c, br);
                vt[i] = bgather(tb, c, bt);
                l0 = fmaf(w[c],          vr[i], fmaf(w[NC + c],     vt[i], l0));
                l1 = fmaf(w[2 * NC + c], vr[i], fmaf(w[3 * NC + c], vt[i], l1));
            }
            part0[p][g] = l0;
            part1[p][g] = l1;
        }
        __syncthreads();
        if (g == 0 && p < 49) {
            float L0 = ba[0], L1 = ba[1];
            #pragma unroll
            for (int s = 0; s < 8; ++s) { L0 += part0[p][s]; L1 += part1[p][s]; }
            float m = fmaxf(L0, L1);
            float e0 = expf(L0 - m), e1 = expf(L1 - m);
            att[p] = e0 / (e0 + e1);
        }
        __syncthreads();
        if (!act) return;

        float a0 = att[p];
        float* po = out + (((size_t)b * NC) << 14) + (y << 7) + x;
        #pragma unroll
        for (int i = 0; i < 32; ++i) {
            int c = c0 + i;
            po[(size_t)c << 14] = fmaf(a0, vr[i] - vt[i], vt[i]);
        }
    } else {
        // ================= global per-pixel fusion ========================
        int b = idx >> 8;                // 256 fuse-blocks per image
        int pix = ((idx & 255) << 6) + p;
        for (int i = tid; i < 2 * TC; i += 512) w[i] = wg[i];

        bool act = owner[((size_t)b << 14) + pix] < 0;  // owned -> roi writes

        const float* pr = rgb + (((size_t)b * NC) << 14) + pix;
        const float* pt = tir + (((size_t)b * NC) << 14) + pix;

        __syncthreads();

        float vr[32], vt[32];
        if (act) {
            float l0 = 0.f, l1 = 0.f;
            #pragma unroll
            for (int i = 0; i < 32; ++i) {
                int c = c0 + i;
                vr[i] = pr[(size_t)c << 14];
                vt[i] = pt[(size_t)c << 14];
                l0 = fmaf(w[c],          vr[i], fmaf(w[NC + c],     vt[i], l0));
                l1 = fmaf(w[2 * NC + c], vr[i], fmaf(w[3 * NC + c], vt[i], l1));
            }
            part0[p][g] = l0;
            part1[p][g] = l1;
        }
        __syncthreads();
        if (g == 0 && act) {
            float L0 = bg[0], L1 = bg[1];
            #pragma unroll
            for (int s = 0; s < 8; ++s) { L0 += part0[p][s]; L1 += part1[p][s]; }
            float m = fmaxf(L0, L1);
            float e0 = expf(L0 - m), e1 = expf(L1 - m);
            att[p] = e0 / (e0 + e1);
        }
        __syncthreads();
        if (!act) return;

        float a0 = att[p];
        float* po = out + (((size_t)b * NC) << 14) + pix;
        #pragma unroll
        for (int i = 0; i < 32; ++i) {
            int c = c0 + i;
            po[(size_t)c << 14] = fmaf(a0, vr[i] - vt[i], vt[i]);
        }
    }
}

// ---------------------------------------------------------------------------
extern "C" void kernel_launch(void* const* d_in, const int* in_sizes, int n_in,
                              void* d_out, int out_size, void* d_ws, size_t ws_size,
                              hipStream_t stream) {
    const float* frgb = (const float*)d_in[0];
    const float* ftir = (const float*)d_in[1];
    const float* argb = (const float*)d_in[2];
    const float* atir = (const float*)d_in[3];
    const float* wg   = (const float*)d_in[4];
    const float* bgp  = (const float*)d_in[5];
    const float* wa   = (const float*)d_in[6];
    const float* bap  = (const float*)d_in[7];
    float* out = (float*)d_out;

    int B = in_sizes[0] / (NC * HW);       // 8
    int N = in_sizes[2] / (B * 3);         // 128
    int npix = B * HW;                     // 131072
    int nRoi = B * N;                      // 1024
    int nFuse = npix / 64;                 // 2048

    int* owner = (int*)d_ws;               // B*H*W ints = 512 KB

    init_owner_k<<<(npix + 255) / 256, 256, 0, stream>>>(owner, npix);
    mark_owner_k<<<(B * N * 49 + 255) / 256, 256, 0, stream>>>(argb, owner, B, N);
    fused_k<<<nRoi + nFuse, 512, 0, stream>>>(frgb, ftir, argb, atir,
                                              wg, bgp, wa, bap,
                                              owner, out, N, nRoi, nFuse);
}

// Round 7
// 188.162 us; speedup vs baseline: 2.5424x; 1.0424x over previous
//
#include <hip/hip_runtime.h>
#include <math.h>

#define ROI 7
#define NC 256          // channels per modality
#define TC 512          // 2*NC concatenated
#define HH 128
#define WW 128
#define HW (HH * WW)    // 16384

// ---------------------------------------------------------------------------
// Owner map: owner[b][y][x] = max anchor index n whose scattered 7x7 patch
// covers (y,x), else -1. Sequential overwrite == "last (max) anchor wins".
// ---------------------------------------------------------------------------
__global__ void init_owner_k(int* __restrict__ owner, int n) {
    int i = blockIdx.x * blockDim.x + threadIdx.x;
    if (i < n) owner[i] = -1;
}

__global__ void mark_owner_k(const float* __restrict__ anchors,
                             int* __restrict__ owner, int B, int N) {
    int i = blockIdx.x * blockDim.x + threadIdx.x;
    int total = B * N * 49;
    if (i >= total) return;
    int p = i % 49;
    int bn = i / 49;
    int n = bn % N;
    int b = bn / N;
    float ax = anchors[(size_t)(b * N + n) * 3 + 0];
    float ay = anchors[(size_t)(b * N + n) * 3 + 1];
    int x0 = (int)truncf(ax - 3.5f); x0 = min(max(x0, 0), WW - ROI);
    int y0 = (int)truncf(ay - 3.5f); y0 = min(max(y0, 0), HH - ROI);
    int x = x0 + (p % 7);
    int y = y0 + (p / 7);
    atomicMax(&owner[((size_t)b << 14) + (y << 7) + x], n);
}

// ---------------------------------------------------------------------------
// Per-point bilinear WEIGHTS exactly per torchvision/reference semantics.
// (Values come from the shared 8x8 corner grid via shuffles.)
// ---------------------------------------------------------------------------
struct BW { float w00, w01, w10, w11; };

__device__ inline BW bilin_weights(float X, float Y) {
    BW r;
    bool valid = (X >= -1.0f) && (X <= (float)WW) && (Y >= -1.0f) && (Y <= (float)HH);
    float x = fmaxf(X, 0.0f), y = fmaxf(Y, 0.0f);
    int ix = (int)floorf(x), iy = (int)floorf(y);
    int xl = min(ix, WW - 1);
    int yl = min(iy, HH - 1);
    float lx = (ix >= WW - 1) ? 0.0f : x - (float)xl;
    float ly = (iy >= HH - 1) ? 0.0f : y - (float)yl;
    float hx = 1.0f - lx, hy = 1.0f - ly;
    float s = valid ? 1.0f : 0.0f;
    r.w00 = hy * hx * s; r.w01 = hy * lx * s;
    r.w10 = ly * hx * s; r.w11 = ly * lx * s;
    return r;
}

// ---------------------------------------------------------------------------
// Merged kernel: fuse-blocks and roi-blocks in ONE launch (independent work:
// fuse writes unowned pixels, roi writes owned pixels; both only read
// features + owner). 1 roi : 2 fuse interleave keeps a mix on each CU.
//
// roi path: lane = 8x8 grid position (ly*8+lx). One wave64 load fetches the
// entire bilinear corner grid for a channel; each point (ly<7,lx<7) gets its
// 4 corners from lanes {p, p+1, p+8, p+9} via 3 __shfl_down. 4x fewer vmem
// instructions than per-corner gathering.
// ---------------------------------------------------------------------------
__global__ __launch_bounds__(512) void fused_k(
        const float* __restrict__ rgb, const float* __restrict__ tir,
        const float* __restrict__ a_rgb, const float* __restrict__ a_tir,
        const float* __restrict__ wg, const float* __restrict__ bg,
        const float* __restrict__ wa, const float* __restrict__ ba,
        const int* __restrict__ owner, float* __restrict__ out,
        int N, int nRoi, int nFuse) {
    __shared__ float w[2 * TC];
    __shared__ float part0[64][9];
    __shared__ float part1[64][9];
    __shared__ float att[64];

    int bid = blockIdx.x;
    int tid = threadIdx.x;

    bool isRoi;
    int idx;
    if (nFuse == 2 * nRoi) {             // interleaved mapping (1 roi : 2 fuse)
        int q = bid / 3, r = bid - 3 * q;
        isRoi = (r == 0);
        idx = isRoi ? q : (bid - q - 1);
    } else {                              // generic fallback
        isRoi = (bid < nRoi);
        idx = isRoi ? bid : (bid - nRoi);
    }

    int p  = tid & 63;
    int g  = tid >> 6;                   // 0..7 -> 32 channels each
    int c0 = g << 5;

    if (isRoi) {
        // ================= ROI align + fuse + owner-gated scatter =========
        int b = idx / N, n = idx % N;
        for (int i = tid; i < 2 * TC; i += 512) w[i] = wa[i];

        int lx = p & 7, ly = p >> 3;     // 8x8 corner-grid position
        bool isPt = (lx < 7) && (ly < 7);

        float axr = a_rgb[(size_t)(b * N + n) * 3 + 0];
        float ayr = a_rgb[(size_t)(b * N + n) * 3 + 1];
        float axt = a_tir[(size_t)(b * N + n) * 3 + 0];
        float ayt = a_tir[(size_t)(b * N + n) * 3 + 1];

        // corner-grid bases (exact: floor(ax-3) == floor of point-0 sample)
        int gx0r = max(0, (int)floorf(axr - 3.0f));
        int gy0r = max(0, (int)floorf(ayr - 3.0f));
        int gx0t = max(0, (int)floorf(axt - 3.0f));
        int gy0t = max(0, (int)floorf(ayt - 3.0f));
        int offr = (min(gy0r + ly, HH - 1) << 7) + min(gx0r + lx, WW - 1);
        int offt = (min(gy0t + ly, HH - 1) << 7) + min(gx0t + lx, WW - 1);

        // per-point sample coords, exactly as reference computes them
        float Xr = (axr - 3.5f) + ((float)lx + 0.5f);
        float Yr = (ayr - 3.5f) + ((float)ly + 0.5f);
        float Xt = (axt - 3.5f) + ((float)lx + 0.5f);
        float Yt = (ayt - 3.5f) + ((float)ly + 0.5f);
        BW br = bilin_weights(Xr, Yr);
        BW bt = bilin_weights(Xt, Yt);

        // scatter position + owner pre-gate (stores only)
        int x0 = (int)truncf(axr - 3.5f); x0 = min(max(x0, 0), WW - ROI);
        int y0 = (int)truncf(ayr - 3.5f); y0 = min(max(y0, 0), HH - ROI);
        int x = x0 + lx, y = y0 + ly;
        bool act = isPt;
        if (act) act = (owner[((size_t)b << 14) + (y << 7) + x] == n);

        const float* rb = rgb + (((size_t)b * NC) << 14);
        const float* tb = tir + (((size_t)b * NC) << 14);

        __syncthreads();

        float vr[32], vt[32];
        float l0 = 0.f, l1 = 0.f;
        #pragma unroll
        for (int i = 0; i < 32; ++i) {
            int c = c0 + i;
            float gr0 = rb[((size_t)c << 14) + offr];
            float gt0 = tb[((size_t)c << 14) + offt];
            float gr1 = __shfl_down(gr0, 1, 64);
            float gr8 = __shfl_down(gr0, 8, 64);
            float gr9 = __shfl_down(gr0, 9, 64);
            float gt1 = __shfl_down(gt0, 1, 64);
            float gt8 = __shfl_down(gt0, 8, 64);
            float gt9 = __shfl_down(gt0, 9, 64);
            vr[i] = br.w00 * gr0 + br.w01 * gr1 + br.w10 * gr8 + br.w11 * gr9;
            vt[i] = bt.w00 * gt0 + bt.w01 * gt1 + bt.w10 * gt8 + bt.w11 * gt9;
            l0 = fmaf(w[c],          vr[i], fmaf(w[NC + c],     vt[i], l0));
            l1 = fmaf(w[2 * NC + c], vr[i], fmaf(w[3 * NC + c], vt[i], l1));
        }
        part0[p][g] = l0;
        part1[p][g] = l1;
        __syncthreads();
        if (g == 0 && isPt) {
            float L0 = ba[0], L1 = ba[1];
            #pragma unroll
            for (int s = 0; s < 8; ++s) { L0 += part0[p][s]; L1 += part1[p][s]; }
            float m = fmaxf(L0, L1);
            float e0 = expf(L0 - m), e1 = expf(L1 - m);
            att[p] = e0 / (e0 + e1);
        }
        __syncthreads();
        if (!act) return;

        float a0 = att[p];
        float* po = out + (((size_t)b * NC) << 14) + (y << 7) + x;
        #pragma unroll
        for (int i = 0; i < 32; ++i) {
            int c = c0 + i;
            po[(size_t)c << 14] = fmaf(a0, vr[i] - vt[i], vt[i]);
        }
    } else {
        // ================= global per-pixel fusion ========================
        int b = idx >> 8;                // 256 fuse-blocks per image
        int pix = ((idx & 255) << 6) + p;
        for (int i = tid; i < 2 * TC; i += 512) w[i] = wg[i];

        bool act = owner[((size_t)b << 14) + pix] < 0;  // owned -> roi writes

        const float* pr = rgb + (((size_t)b * NC) << 14) + pix;
        const float* pt = tir + (((size_t)b * NC) << 14) + pix;

        __syncthreads();

        float vr[32], vt[32];
        if (act) {
            float l0 = 0.f, l1 = 0.f;
            #pragma unroll
            for (int i = 0; i < 32; ++i) {
                int c = c0 + i;
                vr[i] = pr[(size_t)c << 14];
                vt[i] = pt[(size_t)c << 14];
                l0 = fmaf(w[c],          vr[i], fmaf(w[NC + c],     vt[i], l0));
                l1 = fmaf(w[2 * NC + c], vr[i], fmaf(w[3 * NC + c], vt[i], l1));
            }
            part0[p][g] = l0;
            part1[p][g] = l1;
        }
        __syncthreads();
        if (g == 0 && act) {
            float L0 = bg[0], L1 = bg[1];
            #pragma unroll
            for (int s = 0; s < 8; ++s) { L0 += part0[p][s]; L1 += part1[p][s]; }
            float m = fmaxf(L0, L1);
            float e0 = expf(L0 - m), e1 = expf(L1 - m);
            att[p] = e0 / (e0 + e1);
        }
        __syncthreads();
        if (!act) return;

        float a0 = att[p];
        float* po = out + (((size_t)b * NC) << 14) + pix;
        #pragma unroll
        for (int i = 0; i < 32; ++i) {
            int c = c0 + i;
            po[(size_t)c << 14] = fmaf(a0, vr[i] - vt[i], vt[i]);
        }
    }
}

// ---------------------------------------------------------------------------
extern "C" void kernel_launch(void* const* d_in, const int* in_sizes, int n_in,
                              void* d_out, int out_size, void* d_ws, size_t ws_size,
                              hipStream_t stream) {
    const float* frgb = (const float*)d_in[0];
    const float* ftir = (const float*)d_in[1];
    const float* argb = (const float*)d_in[2];
    const float* atir = (const float*)d_in[3];
    const float* wg   = (const float*)d_in[4];
    const float* bgp  = (const float*)d_in[5];
    const float* wa   = (const float*)d_in[6];
    const float* bap  = (const float*)d_in[7];
    float* out = (float*)d_out;

    int B = in_sizes[0] / (NC * HW);       // 8
    int N = in_sizes[2] / (B * 3);         // 128
    int npix = B * HW;                     // 131072
    int nRoi = B * N;                      // 1024
    int nFuse = npix / 64;                 // 2048

    int* owner = (int*)d_ws;               // B*H*W ints = 512 KB

    init_owner_k<<<(npix + 255) / 256, 256, 0, stream>>>(owner, npix);
    mark_owner_k<<<(B * N * 49 + 255) / 256, 256, 0, stream>>>(argb, owner, B, N);
    fused_k<<<nRoi + nFuse, 512, 0, stream>>>(frgb, ftir, argb, atir,
                                              wg, bgp, wa, bap,
                                              owner, out, N, nRoi, nFuse);
}